// Round 5
// baseline (406.433 us; speedup 1.0000x reference)
//
#include <hip/hip_runtime.h>
#include <hip/hip_bf16.h>

#define N_NODES 8192
#define D_FEAT 128

// ws layout: [0, 2MiB) = zn (normalized bf16, pre-swizzled tiles);
// [2MiB] int cnt; [2MiB+16) int4 list[LIST_CAP] for deferred cold pairs.
#define ZN_BYTES (2u * 1024u * 1024u)
#define LIST_CAP 1024

typedef __bf16 bf16x8 __attribute__((ext_vector_type(8)));
typedef float f32x4 __attribute__((ext_vector_type(4)));

// ---- barriers (raw s_barrier; never drain vmcnt to 0 inside the loop) ----
__device__ __forceinline__ void lgkm_barrier() {
  asm volatile("s_waitcnt lgkmcnt(0)\n\ts_barrier" ::: "memory");
}
// Tile-top: per-wave FIFO is [8 gl_lds(t)][16 stores(t-1)] -> vmcnt(16)
// retires exactly the staging loads, leaves all 16 stores in flight.
__device__ __forceinline__ void stage_barrier() {
  asm volatile("s_waitcnt vmcnt(16) lgkmcnt(0)\n\ts_barrier" ::: "memory");
}
__device__ __forceinline__ void vm0_barrier() {
  asm volatile("s_waitcnt vmcnt(0) lgkmcnt(0)\n\ts_barrier" ::: "memory");
}
__device__ __forceinline__ void lgkm_fence() {
  asm volatile("s_waitcnt lgkmcnt(0)" ::: "memory");
}

// Async global->LDS, 16B/lane, linear dest (wave-uniform base + lane*16 —
// satisfied by chunk = i*256 + tid addressing; refcheck-validated R12-R15).
__device__ __forceinline__ void async_copy16(void* lds, const void* g) {
  __builtin_amdgcn_global_load_lds(
      (const __attribute__((address_space(1))) void*)g,
      (__attribute__((address_space(3))) void*)lds, 16, 0, 0);
}

// ---- cold path (fixup kernel only — never called from sim, so sim's
// register allocation is unconstrained). Never taken for the given Gaussian
// inputs: max off-diag cosine ~0.49 << 0.75.
__device__ __attribute__((noinline)) bool lsh_collide(
    const float* __restrict__ z, const float* __restrict__ H, int i, int j) {
  for (int b = 0; b < 64; ++b) {          // 64 bands x 8 bits
    unsigned ci = 0, cj = 0;
    for (int bit = 0; bit < 8; ++bit) {
      int col = b * 8 + bit;
      float di = 0.f, dj = 0.f;
      for (int k = 0; k < D_FEAT; ++k) {
        float h = H[(size_t)k * 512 + col];
        di += z[(size_t)i * D_FEAT + k] * h;
        dj += z[(size_t)j * D_FEAT + k] * h;
      }
      if (di > 0.f) ci |= (1u << bit);
      if (dj > 0.f) cj |= (1u << bit);
    }
    if (ci == cj) return true;
  }
  return false;
}

__device__ __forceinline__ unsigned pack_bf16x2(float x, float y) {
  __hip_bfloat16 bx = __float2bfloat16(x), by = __float2bfloat16(y);
  return (unsigned)(*(unsigned short*)&bx) |
         ((unsigned)(*(unsigned short*)&by) << 16);
}

// ---- pre-kernel: normalize z -> bf16 in the PRE-SWIZZLED tile layout
// (16B chunk c of row r of tile blk at zn[blk*2048 + r*16 + (c^(r&15))]).
// Layout + rounding refcheck-validated (R13-R15). Also zeroes the cold
// counter (ws is poisoned each iteration).
__global__ __launch_bounds__(256) void norm_kernel(const float* __restrict__ z,
                                                   uint4* __restrict__ zn,
                                                   int* __restrict__ cnt) {
  if (blockIdx.x == 0 && threadIdx.x == 0) *cnt = 0;
  int gt = (int)blockIdx.x * 256 + (int)threadIdx.x;
  int row = gt >> 3, oct = gt & 7;        // 8 lanes per row
  const float4* src = (const float4*)(z + (size_t)row * D_FEAT + oct * 16);
  float4 v[4];
#pragma unroll
  for (int c = 0; c < 4; ++c) v[c] = src[c];
  float ss = 0.f;
#pragma unroll
  for (int c = 0; c < 4; ++c)
    ss += v[c].x * v[c].x + v[c].y * v[c].y + v[c].z * v[c].z + v[c].w * v[c].w;
  ss += __shfl_xor(ss, 1);
  ss += __shfl_xor(ss, 2);
  ss += __shfl_xor(ss, 4);
  float inv = rsqrtf(ss);
  int blk = row >> 7, r = row & 127;
  uint4* dst = zn + (size_t)blk * 2048 + r * 16;
#pragma unroll
  for (int c2 = 0; c2 < 2; ++c2) {
    float4 a = v[2 * c2], b = v[2 * c2 + 1];
    uint4 o;
    o.x = pack_bf16x2(a.x * inv, a.y * inv);
    o.y = pack_bf16x2(a.z * inv, a.w * inv);
    o.z = pack_bf16x2(b.x * inv, b.y * inv);
    o.w = pack_bf16x2(b.z * inv, b.w * inv);
    dst[(oct * 2 + c2) ^ (r & 15)] = o;
  }
}

// ---- main kernel (R16): R14 pipeline with ROW-STRIP wave decomposition.
// Wave wv owns 32 rows x 128 cols (tm in {0,1}, tn in 0..7). Each output
// store instr = 64 lanes x 16B = 2 full rows x 512B CONTIGUOUS (vs R14's
// 4 x 256B) -> wider HBM write segments (the R15-measured ~13us residual).
// B fragments tile-invariant in 128 VGPRs (identical in all waves); per-tile
// LDS reads halve to 8 ds_read_b128. FIFO per tile unchanged: [8 gl_lds]
// [16 stores] -> tile-top vmcnt(16) never drains stores. No call in sim.
__global__ __launch_bounds__(256, 2) void sim_kernel(const uint4* __restrict__ zn,
                                                     float* __restrict__ out,
                                                     int* __restrict__ cnt,
                                                     int4* __restrict__ list) {
  __shared__ __align__(16) unsigned char smem[65536];   // buf0 | buf1 (32KB each)

  int tid = threadIdx.x;
  int b = (int)blockIdx.x;
  int bm0 = b & 7;                // XCD id under round-robin dispatch
  int bn = b >> 3;                // 0..63

  int wv = tid >> 6, lane = tid & 63;
  int wm = wv * 32;               // wave's 32-row strip within the 128-row tile
  int m16 = lane & 15, g = lane >> 4;

  // ---- prologue: Bs(bn) -> buf1, As(tile0) -> buf0, both via gl_lds.
  {
    const uint4* gB = zn + (size_t)bn * 2048;
    const uint4* gA = zn + (size_t)(bm0 * 8) * 2048;
#pragma unroll
    for (int i = 0; i < 8; ++i) {
      int c = i * 256 + tid;
      async_copy16(smem + 32768 + c * 16, gB + c);
      async_copy16(smem + c * 16, gA + c);
    }
  }
  vm0_barrier();

  // Hoist ALL B fragments (8 tn x 4 kc) into registers — tile-invariant,
  // statically indexed, identical across waves. buf1 is dead after this ->
  // becomes the odd-parity As buffer.
  bf16x8 fbr[32];
  {
    unsigned short (*Bs)[128] = (unsigned short (*)[128])(smem + 32768);
#pragma unroll
    for (int kc = 0; kc < 4; ++kc) {
      int cs = ((kc * 4 + g) ^ m16) * 8;
#pragma unroll
      for (int tn = 0; tn < 8; ++tn)
        fbr[kc * 8 + tn] = *(const bf16x8*)&Bs[tn * 16 + m16][cs];
    }
  }

  for (int t = 0; t < 8; ++t) {
    int bm = bm0 * 8 + t;
    unsigned char* cur = smem + (t & 1) * 32768;        // As(t), then slabs(t)
    unsigned char* nxt = smem + ((t + 1) & 1) * 32768;  // gl_lds target for As(t+1)

    // B1: all waves' reads of buf(t-1) done (lgkm+barrier); my gl_lds(t)
    // retired (vmcnt(16)); stores(t-1) stay in flight.
    stage_barrier();

    // Async-stage As(t+1) — concurrent with this tile's MFMA + epilogue.
    if (t < 7) {
      const uint4* gA = zn + (size_t)(bm + 1) * 2048;
#pragma unroll
      for (int i = 0; i < 8; ++i) {
        int c = i * 256 + tid;
        async_copy16(nxt + c * 16, gA + c);
      }
    }

    // ---- MFMA: wave -> 32x128 strip, 2x8 tiles of 16x16x32, K=128 ----
    unsigned short (*As)[128] = (unsigned short (*)[128])cur;
    f32x4 acc[2][8] = {};
#pragma unroll
    for (int kc = 0; kc < 4; ++kc) {
      bf16x8 fa[2];
      int cs = ((kc * 4 + g) ^ m16) * 8;
#pragma unroll
      for (int tm = 0; tm < 2; ++tm)
        fa[tm] = *(const bf16x8*)&As[wm + tm * 16 + m16][cs];
#pragma unroll
      for (int tm = 0; tm < 2; ++tm)
#pragma unroll
        for (int tn = 0; tn < 8; ++tn)
          acc[tm][tn] = __builtin_amdgcn_mfma_f32_16x16x32_bf16(fa[tm], fbr[kc * 8 + tn], acc[tm][tn], 0, 0, 0);
    }

    lgkm_barrier();   // B2: all waves' fa reads done before slab writes (same buffer)

    // ---- epilogue: wave-local slab (16 rows x 128 cols fp32 = 8KB),
    // single-buffered per tm (WAR safe: tm0 readback data is consumed by
    // stores before tm1 writes issue; DS ops per wave are in-order).
    // C/D layout: col=lane&15, row=g*4+r. Swizzle chunk' = chunk ^ rs.
    float* slab = (float*)cur + wv * 2048;
#pragma unroll
    for (int tm = 0; tm < 2; ++tm) {
#pragma unroll
      for (int tn = 0; tn < 8; ++tn) {
        int colq = tn * 16 + m16;          // strip-local col 0..127
        int j = bn * 128 + colq;
        f32x4 c = acc[tm][tn];
#pragma unroll
        for (int r = 0; r < 4; ++r) {
          int rs = g * 4 + r;              // slab row 0..15
          int i = bm * 128 + wm + tm * 16 + rs;
          float s = c[r];
          float val = 0.0f;
          if (i == j) {
            val = 1.0f;
          } else if (s > 0.75f) {          // never taken; defer to fixup
            int idx = atomicAdd(cnt, 1);
            if (idx < LIST_CAP) list[idx] = make_int4(i, j, __float_as_int(s), 0);
          }
          slab[rs * 128 + (((colq >> 2) ^ rs) << 2) + (colq & 3)] = val;
        }
      }
      lgkm_fence();   // slab writes complete before cross-lane readback
      // store: 8 instrs, each 2 rows x 512B contiguous (lanes 0-31 = row,
      // lanes 32-63 = row+1; chunk = lane&31, stored at chunk^row).
      int chunk = lane & 31, rh = lane >> 5;
#pragma unroll
      for (int it = 0; it < 8; ++it) {
        int rs = it * 2 + rh;
        f32x4 v = *(const f32x4*)&slab[rs * 128 + ((chunk ^ rs) << 2)];
        int grow = bm * 128 + wm + tm * 16 + rs;
        *(f32x4*)&out[(size_t)grow * N_NODES + bn * 128 + chunk * 4] = v;
      }
    }
  }
}

// ---- cold fixup: resolve deferred (i,j,s) candidates (empty in practice).
__global__ __launch_bounds__(256) void fixup_kernel(const float* __restrict__ z,
                                                    const float* __restrict__ H,
                                                    const int* __restrict__ cnt,
                                                    const int4* __restrict__ list,
                                                    float* __restrict__ out) {
  int n = *cnt;
  if (n > LIST_CAP) n = LIST_CAP;
  for (int e = (int)threadIdx.x; e < n; e += 256) {
    int i = list[e].x, j = list[e].y;
    float s = __int_as_float(list[e].z);
    if (lsh_collide(z, H, i, j)) out[(size_t)i * N_NODES + j] = s;
  }
}

extern "C" void kernel_launch(void* const* d_in, const int* in_sizes, int n_in,
                              void* d_out, int out_size, void* d_ws, size_t ws_size,
                              hipStream_t stream) {
  const float* z = (const float*)d_in[0];   // [8192, 128] fp32
  const float* H = (const float*)d_in[1];   // [128, 512] fp32
  // d_in[2] = edge_index, unused by the reference forward.
  float* out = (float*)d_out;               // [8192, 8192] fp32
  unsigned char* ws = (unsigned char*)d_ws;
  uint4* zn = (uint4*)ws;                   // 2 MiB normalized bf16, pre-swizzled
  int* cnt = (int*)(ws + ZN_BYTES);
  int4* list = (int4*)(ws + ZN_BYTES + 16);
  (void)ws_size;

  norm_kernel<<<256, 256, 0, stream>>>(z, zn, cnt);
  sim_kernel<<<512, 256, 0, stream>>>(zn, out, cnt, list);
  fixup_kernel<<<1, 256, 0, stream>>>(z, H, cnt, list, out);
}

// Round 6
// 277.881 us; speedup vs baseline: 1.4626x; 1.4626x over previous
//
#include <hip/hip_runtime.h>
#include <hip/hip_bf16.h>

#define N_NODES 8192
#define D_FEAT 128

// ws layout: [0, 2MiB) = zn (normalized bf16, pre-swizzled tiles);
// [2MiB] int cnt; [2MiB+16) int4 list[LIST_CAP] for deferred cold pairs.
#define ZN_BYTES (2u * 1024u * 1024u)
#define LIST_CAP 1024

typedef __bf16 bf16x8 __attribute__((ext_vector_type(8)));
typedef float f32x4 __attribute__((ext_vector_type(4)));

// ---- barriers (raw s_barrier; never drain vmcnt to 0 inside the loop) ----
// Tile-top: per-wave FIFO is [8 gl_lds(t)][16 stores(t-1)] -> vmcnt(16)
// retires exactly the staging loads, leaves all 16 stores in flight.
// lgkmcnt(0) before the barrier also guarantees every wave's ds_reads of
// the PREVIOUS As buffer are complete -> safe to gl_lds-overwrite it after.
__device__ __forceinline__ void stage_barrier() {
  asm volatile("s_waitcnt vmcnt(16) lgkmcnt(0)\n\ts_barrier" ::: "memory");
}
__device__ __forceinline__ void vm0_barrier() {
  asm volatile("s_waitcnt vmcnt(0) lgkmcnt(0)\n\ts_barrier" ::: "memory");
}

// Async global->LDS, 16B/lane, linear dest (wave-uniform base + lane*16 —
// satisfied by chunk = i*256 + tid addressing; refcheck-validated R12-R16).
__device__ __forceinline__ void async_copy16(void* lds, const void* g) {
  __builtin_amdgcn_global_load_lds(
      (const __attribute__((address_space(1))) void*)g,
      (__attribute__((address_space(3))) void*)lds, 16, 0, 0);
}

// ---- cold path (fixup kernel only — never called from sim, so sim's
// register allocation is unconstrained). Never taken for the given Gaussian
// inputs: max off-diag cosine ~0.49 << 0.75.
__device__ __attribute__((noinline)) bool lsh_collide(
    const float* __restrict__ z, const float* __restrict__ H, int i, int j) {
  for (int b = 0; b < 64; ++b) {          // 64 bands x 8 bits
    unsigned ci = 0, cj = 0;
    for (int bit = 0; bit < 8; ++bit) {
      int col = b * 8 + bit;
      float di = 0.f, dj = 0.f;
      for (int k = 0; k < D_FEAT; ++k) {
        float h = H[(size_t)k * 512 + col];
        di += z[(size_t)i * D_FEAT + k] * h;
        dj += z[(size_t)j * D_FEAT + k] * h;
      }
      if (di > 0.f) ci |= (1u << bit);
      if (dj > 0.f) cj |= (1u << bit);
    }
    if (ci == cj) return true;
  }
  return false;
}

__device__ __forceinline__ unsigned pack_bf16x2(float x, float y) {
  __hip_bfloat16 bx = __float2bfloat16(x), by = __float2bfloat16(y);
  return (unsigned)(*(unsigned short*)&bx) |
         ((unsigned)(*(unsigned short*)&by) << 16);
}

// ---- pre-kernel: normalize z -> bf16 in the PRE-SWIZZLED tile layout
// (16B chunk c of row r of tile blk at zn[blk*2048 + r*16 + (c^(r&15))]).
// Layout + rounding refcheck-validated (R13-R16). Also zeroes the cold
// counter (ws is poisoned each iteration).
__global__ __launch_bounds__(256) void norm_kernel(const float* __restrict__ z,
                                                   uint4* __restrict__ zn,
                                                   int* __restrict__ cnt) {
  if (blockIdx.x == 0 && threadIdx.x == 0) *cnt = 0;
  int gt = (int)blockIdx.x * 256 + (int)threadIdx.x;
  int row = gt >> 3, oct = gt & 7;        // 8 lanes per row
  const float4* src = (const float4*)(z + (size_t)row * D_FEAT + oct * 16);
  float4 v[4];
#pragma unroll
  for (int c = 0; c < 4; ++c) v[c] = src[c];
  float ss = 0.f;
#pragma unroll
  for (int c = 0; c < 4; ++c)
    ss += v[c].x * v[c].x + v[c].y * v[c].y + v[c].z * v[c].z + v[c].w * v[c].w;
  ss += __shfl_xor(ss, 1);
  ss += __shfl_xor(ss, 2);
  ss += __shfl_xor(ss, 4);
  float inv = rsqrtf(ss);
  int blk = row >> 7, r = row & 127;
  uint4* dst = zn + (size_t)blk * 2048 + r * 16;
#pragma unroll
  for (int c2 = 0; c2 < 2; ++c2) {
    float4 a = v[2 * c2], b = v[2 * c2 + 1];
    uint4 o;
    o.x = pack_bf16x2(a.x * inv, a.y * inv);
    o.y = pack_bf16x2(a.z * inv, a.w * inv);
    o.z = pack_bf16x2(b.x * inv, b.y * inv);
    o.w = pack_bf16x2(b.z * inv, b.w * inv);
    dst[(oct * 2 + c2) ^ (r & 15)] = o;
  }
}

// ---- main kernel (R17): identity-pattern stores fused with candidate search.
// Hot-path output values are S-INDEPENDENT (0 off-diagonal, 1 on diagonal;
// S only feeds the s>0.75 gate, deferred to fixup). So the epilogue slab/
// transpose is deleted: stores are issued right after the staging loads
// (depend on nothing), drain during MFMA. ONE barrier per tile. Quadrant
// decomposition + fbr[16] (64 VGPR, R14-proven no-spill). Per-tile FIFO
// [8 gl_lds][16 stores] -> tile-top vmcnt(16) never drains stores.
__global__ __launch_bounds__(256, 2) void sim_kernel(const uint4* __restrict__ zn,
                                                     float* __restrict__ out,
                                                     int* __restrict__ cnt,
                                                     int4* __restrict__ list) {
  __shared__ __align__(16) unsigned char smem[65536];   // buf0 | buf1 (32KB each)

  int tid = threadIdx.x;
  int b = (int)blockIdx.x;
  int bm0 = b & 7;                // XCD id under round-robin dispatch
  int bn = b >> 3;                // 0..63

  int wv = tid >> 6, lane = tid & 63;
  int wm = (wv >> 1) * 64, wn = (wv & 1) * 64;
  int m16 = lane & 15, g = lane >> 4;

  // Store geometry: instr covers 8 rows x 512B (tid>>5 = row pair-half,
  // tid&31 = 16B chunk within the block's 512B column window).
  int srow = tid >> 5;            // 0..7
  int schunk = tid & 31;          // 0..31

  // ---- prologue: Bs(bn) -> buf1, As(tile0) -> buf0, both via gl_lds.
  {
    const uint4* gB = zn + (size_t)bn * 2048;
    const uint4* gA = zn + (size_t)(bm0 * 8) * 2048;
#pragma unroll
    for (int i = 0; i < 8; ++i) {
      int c = i * 256 + tid;
      async_copy16(smem + 32768 + c * 16, gB + c);
      async_copy16(smem + c * 16, gA + c);
    }
  }
  vm0_barrier();

  // Hoist B fragments into registers (tile-invariant; statically indexed).
  // buf1 becomes the odd-parity As buffer after this (safe: every wave's
  // fbr ds_reads complete before it enters B1(t=0) via lgkmcnt(0)).
  bf16x8 fbr[16];
  {
    unsigned short (*Bs)[128] = (unsigned short (*)[128])(smem + 32768);
#pragma unroll
    for (int kc = 0; kc < 4; ++kc) {
      int cs = ((kc * 4 + g) ^ m16) * 8;
#pragma unroll
      for (int tt = 0; tt < 4; ++tt)
        fbr[kc * 4 + tt] = *(const bf16x8*)&Bs[wn + tt * 16 + m16][cs];
    }
  }

  for (int t = 0; t < 8; ++t) {
    int bm = bm0 * 8 + t;
    unsigned char* cur = smem + (t & 1) * 32768;
    unsigned char* nxt = smem + ((t + 1) & 1) * 32768;

    // B1: my gl_lds(t) retired (vmcnt 16; stores(t-1) stay in flight) and
    // ALL waves' ds_reads of buf(t-1) done (lgkm 0 + barrier) -> safe to
    // overwrite buf(t-1) and to read As(t).
    stage_barrier();

    // Async-stage As(t+1) — concurrent with everything below.
    if (t < 7) {
      const uint4* gA = zn + (size_t)(bm + 1) * 2048;
#pragma unroll
      for (int i = 0; i < 8; ++i) {
        int c = i * 256 + tid;
        async_copy16(nxt + c * 16, gA + c);
      }
    }

    // ---- identity-pattern stores: depend on NOTHING -> issue now, drain
    // under the MFMA. 16 instrs x (8 rows x 512B); diagonal tile (bm==bn,
    // block-uniform scalar branch) writes the I-pattern.
    {
      float* obase = out + (size_t)(bm * 128) * N_NODES + bn * 128;
      if (bm == bn) {
#pragma unroll
        for (int it = 0; it < 16; ++it) {
          int r = it * 8 + srow;
          f32x4 v;
          int c0 = schunk * 4;
          v[0] = (r == c0) ? 1.0f : 0.0f;
          v[1] = (r == c0 + 1) ? 1.0f : 0.0f;
          v[2] = (r == c0 + 2) ? 1.0f : 0.0f;
          v[3] = (r == c0 + 3) ? 1.0f : 0.0f;
          *(f32x4*)&obase[(size_t)r * N_NODES + c0] = v;
        }
      } else {
        f32x4 zv = {0.f, 0.f, 0.f, 0.f};
#pragma unroll
        for (int it = 0; it < 16; ++it) {
          int r = it * 8 + srow;
          *(f32x4*)&obase[(size_t)r * N_NODES + schunk * 4] = zv;
        }
      }
    }

    // ---- MFMA: wave -> 64x64 quadrant, 4x4 tiles of 16x16x32, K=128 ----
    unsigned short (*As)[128] = (unsigned short (*)[128])cur;
    f32x4 acc[4][4] = {};
#pragma unroll
    for (int kc = 0; kc < 4; ++kc) {
      bf16x8 fa[4];
      int cs = ((kc * 4 + g) ^ m16) * 8;
#pragma unroll
      for (int tt = 0; tt < 4; ++tt)
        fa[tt] = *(const bf16x8*)&As[wm + tt * 16 + m16][cs];
#pragma unroll
      for (int tm = 0; tm < 4; ++tm)
#pragma unroll
        for (int tn = 0; tn < 4; ++tn)
          acc[tm][tn] = __builtin_amdgcn_mfma_f32_16x16x32_bf16(fa[tm], fbr[kc * 4 + tn], acc[tm][tn], 0, 0, 0);
    }

    // ---- candidate scan (no S stores). C/D layout: col=lane&15, row=g*4+r.
    // Branch taken only on diagonal sub-tiles (i==j, excluded inside) or
    // genuine cold candidates (deferred to fixup; atomics deepen the next
    // vmcnt wait but stay correct).
#pragma unroll
    for (int tm = 0; tm < 4; ++tm)
#pragma unroll
      for (int tn = 0; tn < 4; ++tn) {
        f32x4 c = acc[tm][tn];
        float m4 = fmaxf(fmaxf(c[0], c[1]), fmaxf(c[2], c[3]));
        if (m4 > 0.75f) {
          int j = bn * 128 + wn + tn * 16 + m16;
#pragma unroll
          for (int r = 0; r < 4; ++r) {
            int i = bm * 128 + wm + tm * 16 + g * 4 + r;
            if (i != j && c[r] > 0.75f) {
              int idx = atomicAdd(cnt, 1);
              if (idx < LIST_CAP)
                list[idx] = make_int4(i, j, __float_as_int(c[r]), 0);
            }
          }
        }
      }
  }
}

// ---- cold fixup: resolve deferred (i,j,s) candidates (empty in practice);
// patches the zeroed background after sim completes (stream-ordered).
__global__ __launch_bounds__(256) void fixup_kernel(const float* __restrict__ z,
                                                    const float* __restrict__ H,
                                                    const int* __restrict__ cnt,
                                                    const int4* __restrict__ list,
                                                    float* __restrict__ out) {
  int n = *cnt;
  if (n > LIST_CAP) n = LIST_CAP;
  for (int e = (int)threadIdx.x; e < n; e += 256) {
    int i = list[e].x, j = list[e].y;
    float s = __int_as_float(list[e].z);
    if (lsh_collide(z, H, i, j)) out[(size_t)i * N_NODES + j] = s;
  }
}

extern "C" void kernel_launch(void* const* d_in, const int* in_sizes, int n_in,
                              void* d_out, int out_size, void* d_ws, size_t ws_size,
                              hipStream_t stream) {
  const float* z = (const float*)d_in[0];   // [8192, 128] fp32
  const float* H = (const float*)d_in[1];   // [128, 512] fp32
  // d_in[2] = edge_index, unused by the reference forward.
  float* out = (float*)d_out;               // [8192, 8192] fp32
  unsigned char* ws = (unsigned char*)d_ws;
  uint4* zn = (uint4*)ws;                   // 2 MiB normalized bf16, pre-swizzled
  int* cnt = (int*)(ws + ZN_BYTES);
  int4* list = (int4*)(ws + ZN_BYTES + 16);
  (void)ws_size;

  norm_kernel<<<256, 256, 0, stream>>>(z, zn, cnt);
  sim_kernel<<<512, 256, 0, stream>>>(zn, out, cnt, list);
  fixup_kernel<<<1, 256, 0, stream>>>(z, H, cnt, list, out);
}

// Round 7
// 268.893 us; speedup vs baseline: 1.5115x; 1.0334x over previous
//
#include <hip/hip_runtime.h>
#include <hip/hip_bf16.h>

#define N_NODES 8192
#define D_FEAT 128

// ws layout: [0, 2MiB) = zn (normalized bf16, pre-swizzled tiles);
// [2MiB] int cnt; [2MiB+16) int4 list[LIST_CAP] for deferred cold pairs.
#define ZN_BYTES (2u * 1024u * 1024u)
#define LIST_CAP 1024

typedef __bf16 bf16x8 __attribute__((ext_vector_type(8)));
typedef float f32x4 __attribute__((ext_vector_type(4)));

// ---- barriers (raw s_barrier; never drain vmcnt to 0 inside the loop) ----
// Tile-top: per-wave FIFO is [8 gl_lds(t)][16 stores(t-1)] -> vmcnt(16)
// retires exactly the staging loads (+ older stores), never the youngest 16
// stores. lgkmcnt(0)+barrier also proves all waves' ds_reads of the previous
// As buffer are done -> safe to gl_lds-overwrite it.
__device__ __forceinline__ void stage_barrier() {
  asm volatile("s_waitcnt vmcnt(16) lgkmcnt(0)\n\ts_barrier" ::: "memory");
}
__device__ __forceinline__ void vm0_barrier() {
  asm volatile("s_waitcnt vmcnt(0) lgkmcnt(0)\n\ts_barrier" ::: "memory");
}

// Async global->LDS, 16B/lane, linear dest (wave-uniform base + lane*16 —
// satisfied by chunk = i*256 + tid addressing; refcheck-validated R12-R17).
__device__ __forceinline__ void async_copy16(void* lds, const void* g) {
  __builtin_amdgcn_global_load_lds(
      (const __attribute__((address_space(1))) void*)g,
      (__attribute__((address_space(3))) void*)lds, 16, 0, 0);
}

// ---- cold path (fixup kernel only — never called from sim, so sim's
// register allocation is unconstrained). Never taken for the given Gaussian
// inputs: max off-diag cosine ~0.49 << 0.75.
__device__ __attribute__((noinline)) bool lsh_collide(
    const float* __restrict__ z, const float* __restrict__ H, int i, int j) {
  for (int b = 0; b < 64; ++b) {          // 64 bands x 8 bits
    unsigned ci = 0, cj = 0;
    for (int bit = 0; bit < 8; ++bit) {
      int col = b * 8 + bit;
      float di = 0.f, dj = 0.f;
      for (int k = 0; k < D_FEAT; ++k) {
        float h = H[(size_t)k * 512 + col];
        di += z[(size_t)i * D_FEAT + k] * h;
        dj += z[(size_t)j * D_FEAT + k] * h;
      }
      if (di > 0.f) ci |= (1u << bit);
      if (dj > 0.f) cj |= (1u << bit);
    }
    if (ci == cj) return true;
  }
  return false;
}

__device__ __forceinline__ unsigned pack_bf16x2(float x, float y) {
  __hip_bfloat16 bx = __float2bfloat16(x), by = __float2bfloat16(y);
  return (unsigned)(*(unsigned short*)&bx) |
         ((unsigned)(*(unsigned short*)&by) << 16);
}

// ---- pre-kernel: normalize z -> bf16 in the PRE-SWIZZLED tile layout
// (16B chunk c of row r of tile blk at zn[blk*2048 + r*16 + (c^(r&15))]).
// Layout + rounding refcheck-validated (R13-R17). Also zeroes the cold
// counter (ws is poisoned each iteration).
__global__ __launch_bounds__(256) void norm_kernel(const float* __restrict__ z,
                                                   uint4* __restrict__ zn,
                                                   int* __restrict__ cnt) {
  if (blockIdx.x == 0 && threadIdx.x == 0) *cnt = 0;
  int gt = (int)blockIdx.x * 256 + (int)threadIdx.x;
  int row = gt >> 3, oct = gt & 7;        // 8 lanes per row
  const float4* src = (const float4*)(z + (size_t)row * D_FEAT + oct * 16);
  float4 v[4];
#pragma unroll
  for (int c = 0; c < 4; ++c) v[c] = src[c];
  float ss = 0.f;
#pragma unroll
  for (int c = 0; c < 4; ++c)
    ss += v[c].x * v[c].x + v[c].y * v[c].y + v[c].z * v[c].z + v[c].w * v[c].w;
  ss += __shfl_xor(ss, 1);
  ss += __shfl_xor(ss, 2);
  ss += __shfl_xor(ss, 4);
  float inv = rsqrtf(ss);
  int blk = row >> 7, r = row & 127;
  uint4* dst = zn + (size_t)blk * 2048 + r * 16;
#pragma unroll
  for (int c2 = 0; c2 < 2; ++c2) {
    float4 a = v[2 * c2], b = v[2 * c2 + 1];
    uint4 o;
    o.x = pack_bf16x2(a.x * inv, a.y * inv);
    o.y = pack_bf16x2(a.z * inv, a.w * inv);
    o.z = pack_bf16x2(b.x * inv, b.y * inv);
    o.w = pack_bf16x2(b.z * inv, b.w * inv);
    dst[(oct * 2 + c2) ^ (r & 15)] = o;
  }
}

// ---- main kernel (R18): write-region / compute-tile DECOUPLING.
// Hot-path output values are S-independent (identity pattern; S feeds only
// the s>0.75 gate, deferred to fixup). So block b:
//   * computes S-tiles (bm0=b&7, bn=b>>3) exactly as R14/R17 (candidate scan),
//   * writes a CONTIGUOUS 512KiB slice out[rows 16b..16b+16) — 64KiB linear
//     per tile iteration, the fill-kernel access pattern (~6.5 TB/s), vs the
//     column-windowed 512B segments of R17 (~5 TB/s, the measured residual).
// Stores depend on nothing -> issued right after staging, drain under MFMA.
// ONE barrier per tile; FIFO per tile [8 gl_lds][16 stores]; tile-top
// vmcnt(16) never drains the youngest stores. fbr[16] quadrant decomposition
// (R14-proven no-spill). No calls in sim.
__global__ __launch_bounds__(256, 2) void sim_kernel(const uint4* __restrict__ zn,
                                                     float* __restrict__ out,
                                                     int* __restrict__ cnt,
                                                     int4* __restrict__ list) {
  __shared__ __align__(16) unsigned char smem[65536];   // buf0 | buf1 (32KB each)

  int tid = threadIdx.x;
  int b = (int)blockIdx.x;
  int bm0 = b & 7;                // XCD id under round-robin dispatch
  int bn = b >> 3;                // 0..63

  int wv = tid >> 6, lane = tid & 63;
  int wm = (wv >> 1) * 64, wn = (wv & 1) * 64;
  int m16 = lane & 15, g = lane >> 4;

  // ---- prologue: Bs(bn) -> buf1, As(tile0) -> buf0, both via gl_lds.
  {
    const uint4* gB = zn + (size_t)bn * 2048;
    const uint4* gA = zn + (size_t)(bm0 * 8) * 2048;
#pragma unroll
    for (int i = 0; i < 8; ++i) {
      int c = i * 256 + tid;
      async_copy16(smem + 32768 + c * 16, gB + c);
      async_copy16(smem + c * 16, gA + c);
    }
  }
  vm0_barrier();

  // Hoist B fragments into registers (tile-invariant; statically indexed).
  // buf1 becomes the odd-parity As buffer after this (safe: every wave's
  // fbr ds_reads complete before it enters B1(t=0) via lgkmcnt(0)).
  bf16x8 fbr[16];
  {
    unsigned short (*Bs)[128] = (unsigned short (*)[128])(smem + 32768);
#pragma unroll
    for (int kc = 0; kc < 4; ++kc) {
      int cs = ((kc * 4 + g) ^ m16) * 8;
#pragma unroll
      for (int tt = 0; tt < 4; ++tt)
        fbr[kc * 4 + tt] = *(const bf16x8*)&Bs[wn + tt * 16 + m16][cs];
    }
  }

  for (int t = 0; t < 8; ++t) {
    int bm = bm0 * 8 + t;
    unsigned char* cur = smem + (t & 1) * 32768;
    unsigned char* nxt = smem + ((t + 1) & 1) * 32768;

    // B1: my gl_lds(t) retired (vmcnt 16; youngest stores stay in flight)
    // and ALL waves' ds_reads of buf(t-1) done (lgkm 0 + barrier).
    stage_barrier();

    // Async-stage As(t+1) — concurrent with everything below.
    if (t < 7) {
      const uint4* gA = zn + (size_t)(bm + 1) * 2048;
#pragma unroll
      for (int i = 0; i < 8; ++i) {
        int c = i * 256 + tid;
        async_copy16(nxt + c * 16, gA + c);
      }
    }

    // ---- identity-pattern stores: 64KiB CONTIGUOUS per tile (rows
    // 16b+2t, 16b+2t+1 of out). Depend on nothing -> drain under MFMA.
    {
      f32x4* outq = (f32x4*)out + ((size_t)b << 15) + (size_t)t * 4096;
#pragma unroll
      for (int it = 0; it < 16; ++it) {
        int loc = it * 256 + tid;                // 0..4095 (16B chunks)
        int row = (b << 4) + (t << 1) + (loc >> 11);
        int col0 = (loc & 2047) << 2;
        f32x4 v;
        v[0] = (col0 == row) ? 1.0f : 0.0f;
        v[1] = (col0 + 1 == row) ? 1.0f : 0.0f;
        v[2] = (col0 + 2 == row) ? 1.0f : 0.0f;
        v[3] = (col0 + 3 == row) ? 1.0f : 0.0f;
        outq[loc] = v;
      }
    }

    // ---- MFMA: wave -> 64x64 quadrant, 4x4 tiles of 16x16x32, K=128 ----
    unsigned short (*As)[128] = (unsigned short (*)[128])cur;
    f32x4 acc[4][4] = {};
#pragma unroll
    for (int kc = 0; kc < 4; ++kc) {
      bf16x8 fa[4];
      int cs = ((kc * 4 + g) ^ m16) * 8;
#pragma unroll
      for (int tt = 0; tt < 4; ++tt)
        fa[tt] = *(const bf16x8*)&As[wm + tt * 16 + m16][cs];
#pragma unroll
      for (int tm = 0; tm < 4; ++tm)
#pragma unroll
        for (int tn = 0; tn < 4; ++tn)
          acc[tm][tn] = __builtin_amdgcn_mfma_f32_16x16x32_bf16(fa[tm], fbr[kc * 4 + tn], acc[tm][tn], 0, 0, 0);
    }

    // ---- candidate scan (no S stores). C/D layout: col=lane&15, row=g*4+r.
    // Branch taken only on diagonal sub-tiles (i==j, excluded inside) or
    // genuine cold candidates (deferred to fixup; atomics deepen the next
    // vmcnt wait but stay correct).
#pragma unroll
    for (int tm = 0; tm < 4; ++tm)
#pragma unroll
      for (int tn = 0; tn < 4; ++tn) {
        f32x4 c = acc[tm][tn];
        float m4 = fmaxf(fmaxf(c[0], c[1]), fmaxf(c[2], c[3]));
        if (m4 > 0.75f) {
          int j = bn * 128 + wn + tn * 16 + m16;
#pragma unroll
          for (int r = 0; r < 4; ++r) {
            int i = bm * 128 + wm + tm * 16 + g * 4 + r;
            if (i != j && c[r] > 0.75f) {
              int idx = atomicAdd(cnt, 1);
              if (idx < LIST_CAP)
                list[idx] = make_int4(i, j, __float_as_int(c[r]), 0);
            }
          }
        }
      }
  }
}

// ---- cold fixup: resolve deferred (i,j,s) candidates (empty in practice);
// separate launch is REQUIRED for coherence: its patch writes must not WAW-
// race other XCDs' dirty-L2 zero lines — the kernel boundary's cache
// writeback orders them.
__global__ __launch_bounds__(256) void fixup_kernel(const float* __restrict__ z,
                                                    const float* __restrict__ H,
                                                    const int* __restrict__ cnt,
                                                    const int4* __restrict__ list,
                                                    float* __restrict__ out) {
  int n = *cnt;
  if (n > LIST_CAP) n = LIST_CAP;
  for (int e = (int)threadIdx.x; e < n; e += 256) {
    int i = list[e].x, j = list[e].y;
    float s = __int_as_float(list[e].z);
    if (lsh_collide(z, H, i, j)) out[(size_t)i * N_NODES + j] = s;
  }
}

extern "C" void kernel_launch(void* const* d_in, const int* in_sizes, int n_in,
                              void* d_out, int out_size, void* d_ws, size_t ws_size,
                              hipStream_t stream) {
  const float* z = (const float*)d_in[0];   // [8192, 128] fp32
  const float* H = (const float*)d_in[1];   // [128, 512] fp32
  // d_in[2] = edge_index, unused by the reference forward.
  float* out = (float*)d_out;               // [8192, 8192] fp32
  unsigned char* ws = (unsigned char*)d_ws;
  uint4* zn = (uint4*)ws;                   // 2 MiB normalized bf16, pre-swizzled
  int* cnt = (int*)(ws + ZN_BYTES);
  int4* list = (int4*)(ws + ZN_BYTES + 16);
  (void)ws_size;

  norm_kernel<<<256, 256, 0, stream>>>(z, zn, cnt);
  sim_kernel<<<512, 256, 0, stream>>>(zn, out, cnt, list);
  fixup_kernel<<<1, 256, 0, stream>>>(z, H, cnt, list, out);
}